// Round 17
// baseline (174.582 us; speedup 1.0000x reference)
//
#include <hip/hip_runtime.h>
#include <hip/hip_fp16.h>

#define NDIM 256
#define LUT_N 8192
#define LUT_BLOCKS (LUT_N / 4)   // 4 waves/block, one LUT row per wave
#define SCAN_BLK 1024

typedef _Float16 h2 __attribute__((ext_vector_type(2)));
typedef __fp16   g2 __attribute__((ext_vector_type(2)));
union HU { unsigned u; h2 h; g2 g; };

__device__ __forceinline__ float fdot2f(unsigned a_bits, unsigned b_bits, float c)
{
    HU a, b; a.u = a_bits; b.u = b_bits;
#if __has_builtin(__builtin_amdgcn_fdot2)
    return __builtin_amdgcn_fdot2(a.h, b.h, c, false);
#else
    return fmaf((float)a.h.x, (float)b.h.x, fmaf((float)a.h.y, (float)b.h.y, c));
#endif
}

// ---------------------------------------------------------------------------
// Fused prep kernel, four independent block ranges:
//   [0, LUT_BLOCKS)                   : LUT build (nearest-neighbor, fp16 x4)
//   [+histBlocks)                     : histogram of col with rank capture
//   [+tBlocks)                        : nf -> nft fp16 transpose
//   [+lwBlocks)                       : lw0,lw1 -> fp16 pair-packed lwpk
// ---------------------------------------------------------------------------
__global__ __launch_bounds__(256) void prep_kernel(
    const float* __restrict__ w1, const float* __restrict__ b1,
    const float* __restrict__ w2, const float* __restrict__ b2,
    const float* __restrict__ w3, const float* __restrict__ b3,
    uint2* __restrict__ lutp,
    const int* __restrict__ col, int E,
    int* __restrict__ counts, int* __restrict__ rank,
    const float* __restrict__ nf, uint2* __restrict__ nft,
    const float* __restrict__ lw0, const float* __restrict__ lw1,
    uint2* __restrict__ lwpk,
    int histBlocks, int tBlocks, int N)
{
    if (blockIdx.x >= (unsigned)(LUT_BLOCKS + histBlocks + tBlocks)) {
        int t = (blockIdx.x - LUT_BLOCKS - histBlocks - tBlocks) * 256 + threadIdx.x;
        if (t < 32 * 64) {
            int i = t >> 6, lane = t & 63;
            HU w0p, w1p;
            w0p.h = h2{(_Float16)lw0[(2 * i) * 64 + lane], (_Float16)lw0[(2 * i + 1) * 64 + lane]};
            w1p.h = h2{(_Float16)lw1[(2 * i) * 64 + lane], (_Float16)lw1[(2 * i + 1) * 64 + lane]};
            lwpk[t] = make_uint2(w0p.u, w1p.u);
        }
        return;
    }
    if (blockIdx.x >= (unsigned)(LUT_BLOCKS + histBlocks)) {
        int t = (blockIdx.x - LUT_BLOCKS - histBlocks) * 256 + threadIdx.x;
        if (t < N * 64) {
            int n = t >> 6, m = t & 63;
            const float* nr = nf + (size_t)n * NDIM;
            float s0 = nr[m];
            float3 s1 = ((const float3*)(nr + 64))[m];
            HU a, b;
            a.h = h2{(_Float16)s1.x, (_Float16)s1.y};
            b.h = h2{(_Float16)s1.z, (_Float16)s0};
            nft[t] = make_uint2(a.u, b.u);
        }
        return;
    }
    if (blockIdx.x >= (unsigned)LUT_BLOCKS) {
        int i = (blockIdx.x - LUT_BLOCKS) * 256 + threadIdx.x;
        if (i < E) rank[i] = atomicAdd(&counts[col[i]], 1);
        return;
    }

    __shared__ float h1s[4][64];
    __shared__ float h2s[4][64];
    int tid = threadIdx.x;
    int wave = tid >> 6;
    int j = tid & 63;
    int p = blockIdx.x * 4 + wave;
    float r = 0.5f + (4.5f / (float)(LUT_N - 1)) * (float)p;

    const float cnorm = 0.6324555320336759f;  // sqrt(2/5)
    float acc = b1[j];
    #pragma unroll
    for (int k = 0; k < 8; ++k) {
        float freq = (float)(k + 1) * (3.14159265358979323846f / 5.0f);
        acc = fmaf(cnorm * sinf(freq * r) / r, w1[k * 64 + j], acc);
    }
    h1s[wave][j] = acc / (1.0f + expf(-acc));
    __syncthreads();

    acc = b2[j];
    #pragma unroll 8
    for (int m = 0; m < 64; ++m) acc = fmaf(h1s[wave][m], w2[m * 64 + j], acc);
    h2s[wave][j] = acc / (1.0f + expf(-acc));
    __syncthreads();

    float u = r * 0.2f;
    float u5 = u * u * u * u * u;
    float env = (u < 1.0f) ? (1.0f - 21.0f * u5 + 35.0f * u5 * u - 15.0f * u5 * u * u) : 0.0f;

    float o0 = b3[j], o1 = b3[64 + j], o2 = b3[128 + j], o3 = b3[192 + j];
    #pragma unroll 8
    for (int m = 0; m < 64; ++m) {
        float hv = h2s[wave][m];
        const float* wr = w3 + m * 256;
        o0 = fmaf(hv, wr[j],       o0);
        o1 = fmaf(hv, wr[64 + j],  o1);
        o2 = fmaf(hv, wr[128 + j], o2);
        o3 = fmaf(hv, wr[192 + j], o3);
    }
    HU uab, ucd;
    uab.h = h2{(_Float16)(o0 * env), (_Float16)(o1 * env)};
    ucd.h = h2{(_Float16)(o2 * env), (_Float16)(o3 * env)};
    lutp[p * 64 + j] = make_uint2(uab.u, ucd.u);
}

// ---------------------------------------------------------------------------
// Coalesced per-chunk scan; chunk totals scanned in-wave by consumers.
// row_ptr[n] == loc[n] + boff[n >> 10], boff = wave-scan of btot.
// ---------------------------------------------------------------------------
__global__ __launch_bounds__(SCAN_BLK) void scan1_kernel(
    const int* __restrict__ counts, int* __restrict__ loc,
    int* __restrict__ btot, int N)
{
    __shared__ int sh[SCAN_BLK];
    int t = threadIdx.x;
    int idx = blockIdx.x * SCAN_BLK + t;
    int v = (idx < N) ? counts[idx] : 0;
    sh[t] = v;
    __syncthreads();
    int acc = v;
    for (int o = 1; o < SCAN_BLK; o <<= 1) {
        int add = (t >= o) ? sh[t - o] : 0;
        __syncthreads();
        acc += add;
        sh[t] = acc;
        __syncthreads();
    }
    if (idx <= N) loc[idx] = acc - v;   // exclusive within chunk
    if (t == SCAN_BLK - 1) btot[blockIdx.x] = acc;
}

// In-wave exclusive scan of btot (nb <= 64); lane i holds boff[i].
__device__ __forceinline__ int btot_scan(const int* __restrict__ btot, int nb, int lane)
{
    int v = (lane < nb) ? btot[lane] : 0;
    int acc = v;
    #pragma unroll
    for (int o = 1; o < 64; o <<= 1) {
        int up = __shfl_up(acc, o);
        if (lane >= o) acc += up;
    }
    return acc - v;
}

// ---------------------------------------------------------------------------
// Atomic-free scatter: p = loc[col] + boff[col>>10] + rank.
// em = uint4{ h2(shx,shy), h2(shz,0), rsrc | i0<<16, 0 }; N <= 65536.
// ---------------------------------------------------------------------------
__global__ __launch_bounds__(256) void scatter_kernel(
    const int* __restrict__ row, const int* __restrict__ col,
    const float* __restrict__ evec, const float* __restrict__ elen,
    int E, const int* __restrict__ loc, const int* __restrict__ btot, int nb,
    const int* __restrict__ rank, uint4* __restrict__ em)
{
    int lane = threadIdx.x & 63;
    int excl = btot_scan(btot, nb, lane);   // lane i: boff[i]

    int i = blockIdx.x * 256 + threadIdx.x;
    if (i < E) {
        int c = col[i];
        int p = loc[c] + __shfl(excl, c >> 10) + rank[i];
        float vx = evec[3 * i + 0], vy = evec[3 * i + 1], vz = evec[3 * i + 2];
        float inv = rsqrtf(vx * vx + vy * vy + vz * vz) * 1.7320508075688772f; // sqrt(3)/|v|
        float x = (elen[i] - 0.5f) * ((float)(LUT_N - 1) / 4.5f);
        int i0 = (int)(x + 0.5f);          // nearest-neighbor index
        i0 = i0 < 0 ? 0 : (i0 > LUT_N - 1 ? LUT_N - 1 : i0);
        HU a, b;
        a.h = h2{(_Float16)(vx * inv), (_Float16)(vy * inv)};
        b.h = h2{(_Float16)(vz * inv), (_Float16)0.0f};
        unsigned packed = (unsigned)row[i] | ((unsigned)i0 << 16);
        em[p] = make_uint4(a.u, b.u, packed, 0u);
    }
}

// ---------------------------------------------------------------------------
// Heavy kernel: 256-thread blocks = 4 INDEPENDENT waves, one node per wave.
// Metadata em[j] wave-uniform -> SGPR s_load (start/end readfirstlane-forced).
// 16-stage named-variable pipeline (2x 8-stage ping-pong) with
// sched_barrier(0)-pinned {accum 8 | load 8} clusters: 16-32 VMEM in flight
// per wave (St = 4 VGPRs -> ~100 VGPR total, no spill; r11's spill was 9/stage).
// fp16 pair-packed epilogue (r16).
// ---------------------------------------------------------------------------
struct St {
    uint2 L;                 // 4x fp16: wa,wb | wc,wd (nearest LUT entry)
    uint2 sv;                // half2(s1x,s1y), half2(s1z,s0)
    unsigned sh_xy, sh_z0;   // half2 bits (wave-uniform -> SGPR)
};

__device__ __forceinline__ St stage_load(int j, int lane,
                                         const uint4* __restrict__ em,
                                         const uint2* __restrict__ lutp,
                                         const uint2* __restrict__ nft)
{
    St s;
    uint4 md = em[j];                        // uniform address -> s_load_dwordx4
    s.sh_xy = md.x;
    s.sh_z0 = md.y;
    int rsrc = (int)(md.z & 0xFFFFu);
    int i0 = (int)(md.z >> 16);
    s.L = lutp[i0 * 64 + lane];
    s.sv = nft[(size_t)rsrc * 64 + lane];
    return s;
}

__device__ __forceinline__ void accum_st(const St& s, float& acc0, float& accx,
                                         float& accy, float& accz)
{
    HU lab, lcd, svxy, svzs, shxy, shz0;
    lab.u = s.L.x;  lcd.u = s.L.y;
    svxy.u = s.sv.x; svzs.u = s.sv.y; shxy.u = s.sh_xy; shz0.u = s.sh_z0;

    float wa = (float)lab.h.x, wb = (float)lab.h.y;
    float wc = (float)lcd.h.x, wd = (float)lcd.h.y;

    // dot = s1 . sh   (second fdot2's y-lane multiplies by packed 0)
    float dot = fdot2f(s.sv.x, s.sh_xy, 0.0f);
    dot = fdot2f(s.sv.y, s.sh_z0, dot);

    float s0 = (float)svzs.h.y;
    acc0 = fmaf(wa, s0, fmaf(wd, dot, acc0));
    float wcs0 = wc * s0;
    accx = fmaf(wb, (float)svxy.h.x, fmaf(wcs0, (float)shxy.h.x, accx));
    accy = fmaf(wb, (float)svxy.h.y, fmaf(wcs0, (float)shxy.h.y, accy));
    accz = fmaf(wb, (float)svzs.h.x, fmaf(wcs0, (float)shz0.h.x, accz));
}

#define LOAD8(v, base)                                        \
    v##0 = stage_load((base) + 0, lane, em, lutp, nft);       \
    v##1 = stage_load((base) + 1, lane, em, lutp, nft);       \
    v##2 = stage_load((base) + 2, lane, em, lutp, nft);       \
    v##3 = stage_load((base) + 3, lane, em, lutp, nft);       \
    v##4 = stage_load((base) + 4, lane, em, lutp, nft);       \
    v##5 = stage_load((base) + 5, lane, em, lutp, nft);       \
    v##6 = stage_load((base) + 6, lane, em, lutp, nft);       \
    v##7 = stage_load((base) + 7, lane, em, lutp, nft);

#define ACC8(v)                                               \
    accum_st(v##0, acc0, accx, accy, accz);                   \
    accum_st(v##1, acc0, accx, accy, accz);                   \
    accum_st(v##2, acc0, accx, accy, accz);                   \
    accum_st(v##3, acc0, accx, accy, accz);                   \
    accum_st(v##4, acc0, accx, accy, accz);                   \
    accum_st(v##5, acc0, accx, accy, accz);                   \
    accum_st(v##6, acc0, accx, accy, accz);                   \
    accum_st(v##7, acc0, accx, accy, accz);

__global__ __launch_bounds__(256, 4) void node_kernel(
    const float* __restrict__ nf,
    const uint2* __restrict__ nft,
    const uint2* __restrict__ lutp,
    const int* __restrict__ loc,
    const int* __restrict__ btot, int nb,
    const uint4* __restrict__ em,
    const uint2* __restrict__ lwpk,
    const float* __restrict__ g0,
    const float* __restrict__ be0,
    const float* __restrict__ g1,
    float* __restrict__ out,
    int N)
{
    __shared__ uint4 agp[4][32];   // [wave][pair] = fp16x2 {a0,x,y,z} pairs
    int tid = threadIdx.x;
    int wave = tid >> 6;
    int lane = tid & 63;
    int n = blockIdx.x * 4 + wave;

    int excl = btot_scan(btot, nb, lane);   // lane i: boff[i]

    if (n >= N) return;               // wave-uniform exit, no barriers used

    int start = loc[n]     + __shfl(excl, n >> 10);
    int end   = loc[n + 1] + __shfl(excl, (n + 1) >> 10);
    start = __builtin_amdgcn_readfirstlane(start);   // keep em[j] on scalar path
    end   = __builtin_amdgcn_readfirstlane(end);

    float acc0 = 0.0f, accx = 0.0f, accy = 0.0f, accz = 0.0f;

    int j = start;
    if (end - start >= 16) {
        St a0, a1, a2, a3, a4, a5, a6, a7;
        St b0, b1, b2, b3, b4, b5, b6, b7;
        LOAD8(a, j);
        LOAD8(b, j + 8);
        j += 16;
        for (; j + 16 <= end; j += 16) {
            __builtin_amdgcn_sched_barrier(0);
            ACC8(a);
            __builtin_amdgcn_sched_barrier(0);
            LOAD8(a, j);
            __builtin_amdgcn_sched_barrier(0);
            ACC8(b);
            __builtin_amdgcn_sched_barrier(0);
            LOAD8(b, j + 8);
        }
        __builtin_amdgcn_sched_barrier(0);
        ACC8(a);
        ACC8(b);
    } else if (end - start >= 8) {
        St a0, a1, a2, a3, a4, a5, a6, a7;
        LOAD8(a, j);
        j += 8;
        __builtin_amdgcn_sched_barrier(0);
        ACC8(a);
    }
    for (; j < end; ++j) {
        St s = stage_load(j, lane, em, lutp, nft);
        accum_st(s, acc0, accx, accy, accz);
    }

    // Pair-pack agg to fp16 and stash in LDS (even lanes write pair lane>>1).
    const float INVS2 = 0.7071067811865476f;
    float v0 = acc0 * INVS2, v1 = accx * INVS2, v2 = accy * INVS2, v3 = accz * INVS2;
    float p0 = __shfl_xor(v0, 1);
    float p1 = __shfl_xor(v1, 1);
    float p2 = __shfl_xor(v2, 1);
    float p3 = __shfl_xor(v3, 1);
    if (!(lane & 1)) {
        HU u0, u1, u2, u3;
        u0.g = __builtin_amdgcn_cvt_pkrtz(v0, p0);
        u1.g = __builtin_amdgcn_cvt_pkrtz(v1, p1);
        u2.g = __builtin_amdgcn_cvt_pkrtz(v2, p2);
        u3.g = __builtin_amdgcn_cvt_pkrtz(v3, p3);
        agp[wave][lane >> 1] = make_uint4(u0.u, u1.u, u2.u, u3.u);
    }
    // wave-private LDS; DS pipe in-order within a wave -> no barrier

    float a0 = 0.0f, t1x = 0.0f, t1y = 0.0f, t1z = 0.0f;
    #pragma unroll 8
    for (int i = 0; i < 32; ++i) {
        uint2 wp = lwpk[i * 64 + lane];   // h2(w0 pair), h2(w1 pair)
        uint4 gp = agp[wave][i];          // broadcast ds_read_b128
        a0  = fdot2f(gp.x, wp.x, a0);
        t1x = fdot2f(gp.y, wp.y, t1x);
        t1y = fdot2f(gp.z, wp.y, t1y);
        t1z = fdot2f(gp.w, wp.y, t1z);
    }
    const float sc = 0.125f;  // 1/sqrt(64)
    a0 *= sc; t1x *= sc; t1y *= sc; t1z *= sc;

    // layernorm over a0 across 64 lanes
    float mu = a0;
    #pragma unroll
    for (int o = 32; o > 0; o >>= 1) mu += __shfl_xor(mu, o);
    mu *= (1.0f / 64.0f);
    float d = a0 - mu;
    float var = d * d;
    #pragma unroll
    for (int o = 32; o > 0; o >>= 1) var += __shfl_xor(var, o);
    var *= (1.0f / 64.0f);
    float o0 = g0[lane] * d * rsqrtf(var + 1e-5f) + be0[lane];

    // RMS over vnorm2 across 64 lanes
    float vn = t1x * t1x + t1y * t1y + t1z * t1z;
    float ms = vn;
    #pragma unroll
    for (int o = 32; o > 0; o >>= 1) ms += __shfl_xor(ms, o);
    ms *= (1.0f / 64.0f);
    float rinv = rsqrtf(ms + 1e-5f);
    float gg = g1[lane];

    size_t b = (size_t)n * NDIM;
    out[b + lane] = nf[b + lane] + o0;
    float3 rv = ((const float3*)(nf + b + 64))[lane];
    float3 ov;
    ov.x = rv.x + gg * t1x * rinv;
    ov.y = rv.y + gg * t1y * rinv;
    ov.z = rv.z + gg * t1z * rinv;
    ((float3*)(out + b + 64))[lane] = ov;
}

// ---------------------------------------------------------------------------
extern "C" void kernel_launch(void* const* d_in, const int* in_sizes, int n_in,
                              void* d_out, int out_size, void* d_ws, size_t ws_size,
                              hipStream_t stream)
{
    const float* nf   = (const float*)d_in[0];
    const int*   eidx = (const int*)d_in[1];
    const float* evec = (const float*)d_in[2];
    const float* elen = (const float*)d_in[3];
    const float* w1   = (const float*)d_in[4];
    const float* b1   = (const float*)d_in[5];
    const float* w2   = (const float*)d_in[6];
    const float* b2   = (const float*)d_in[7];
    const float* w3   = (const float*)d_in[8];
    const float* b3   = (const float*)d_in[9];
    const float* lw0  = (const float*)d_in[10];
    const float* lw1  = (const float*)d_in[11];
    const float* g0   = (const float*)d_in[12];
    const float* be0  = (const float*)d_in[13];
    const float* g1   = (const float*)d_in[14];

    int N = in_sizes[0] / NDIM;
    int E = in_sizes[3];

    int nb = (N + SCAN_BLK) / SCAN_BLK;   // chunks covering idx range [0, N]

    char* ws = (char*)d_ws;
    size_t off_b = 0;
    auto align256 = [&]() { off_b = (off_b + 255) & ~(size_t)255; };
    uint2* lutp = (uint2*)(ws + off_b);   off_b += (size_t)LUT_N * 64 * 8;    align256();
    int* counts = (int*)(ws + off_b);     off_b += (size_t)N * 4;             align256();
    int* loc = (int*)(ws + off_b);        off_b += (size_t)(N + 1) * 4;       align256();
    int* btot = (int*)(ws + off_b);       off_b += (size_t)nb * 4;            align256();
    int* rank = (int*)(ws + off_b);       off_b += (size_t)E * 4;             align256();
    uint4* em = (uint4*)(ws + off_b);     off_b += (size_t)E * 16;            align256();
    uint2* nft = (uint2*)(ws + off_b);    off_b += (size_t)N * 64 * 8;        align256();
    uint2* lwpk = (uint2*)(ws + off_b);   off_b += (size_t)32 * 64 * 8;

    const int* row = eidx;
    const int* col = eidx + E;

    int histBlocks = (E + 255) / 256;
    int tBlocks = (N * 64 + 255) / 256;
    int lwBlocks = (32 * 64 + 255) / 256;

    hipMemsetAsync(counts, 0, (size_t)N * 4, stream);
    prep_kernel<<<LUT_BLOCKS + histBlocks + tBlocks + lwBlocks, 256, 0, stream>>>(
        w1, b1, w2, b2, w3, b3, lutp, col, E, counts, rank, nf, nft,
        lw0, lw1, lwpk, histBlocks, tBlocks, N);
    scan1_kernel<<<nb, SCAN_BLK, 0, stream>>>(counts, loc, btot, N);
    scatter_kernel<<<(E + 255) / 256, 256, 0, stream>>>(row, col, evec, elen, E,
                                                        loc, btot, nb, rank, em);
    node_kernel<<<(N + 3) / 4, 256, 0, stream>>>(nf, nft, lutp, loc, btot, nb, em,
                                                 lwpk, g0, be0, g1,
                                                 (float*)d_out, N);
}

// Round 18
// 149.312 us; speedup vs baseline: 1.1692x; 1.1692x over previous
//
#include <hip/hip_runtime.h>
#include <hip/hip_fp16.h>

#define NDIM 256
#define LUT_N 4096
#define LUT_BLOCKS (LUT_N / 4)   // 4 waves/block, one LUT row per wave
#define SCAN_BLK 1024

typedef _Float16 h2 __attribute__((ext_vector_type(2)));
typedef __fp16   g2 __attribute__((ext_vector_type(2)));
union HU { unsigned u; h2 h; g2 g; };

__device__ __forceinline__ float fdot2f(unsigned a_bits, unsigned b_bits, float c)
{
    HU a, b; a.u = a_bits; b.u = b_bits;
#if __has_builtin(__builtin_amdgcn_fdot2)
    return __builtin_amdgcn_fdot2(a.h, b.h, c, false);
#else
    return fmaf((float)a.h.x, (float)b.h.x, fmaf((float)a.h.y, (float)b.h.y, c));
#endif
}

// ---------------------------------------------------------------------------
// Fused prep kernel, four independent block ranges:
//   [0, LUT_BLOCKS)                   : LUT build (nearest-neighbor, fp16 x4)
//   [+histBlocks)                     : histogram of col with rank capture
//   [+tBlocks)                        : nf -> nft fp16 transpose
//   [+lwBlocks)                       : lw0,lw1 -> fp16 pair-packed lwpk
// ---------------------------------------------------------------------------
__global__ __launch_bounds__(256) void prep_kernel(
    const float* __restrict__ w1, const float* __restrict__ b1,
    const float* __restrict__ w2, const float* __restrict__ b2,
    const float* __restrict__ w3, const float* __restrict__ b3,
    uint2* __restrict__ lutp,
    const int* __restrict__ col, int E,
    int* __restrict__ counts, int* __restrict__ rank,
    const float* __restrict__ nf, uint2* __restrict__ nft,
    const float* __restrict__ lw0, const float* __restrict__ lw1,
    uint2* __restrict__ lwpk,
    int histBlocks, int tBlocks, int N)
{
    if (blockIdx.x >= (unsigned)(LUT_BLOCKS + histBlocks + tBlocks)) {
        int t = (blockIdx.x - LUT_BLOCKS - histBlocks - tBlocks) * 256 + threadIdx.x;
        if (t < 32 * 64) {
            int i = t >> 6, lane = t & 63;
            HU w0p, w1p;
            w0p.h = h2{(_Float16)lw0[(2 * i) * 64 + lane], (_Float16)lw0[(2 * i + 1) * 64 + lane]};
            w1p.h = h2{(_Float16)lw1[(2 * i) * 64 + lane], (_Float16)lw1[(2 * i + 1) * 64 + lane]};
            lwpk[t] = make_uint2(w0p.u, w1p.u);
        }
        return;
    }
    if (blockIdx.x >= (unsigned)(LUT_BLOCKS + histBlocks)) {
        int t = (blockIdx.x - LUT_BLOCKS - histBlocks) * 256 + threadIdx.x;
        if (t < N * 64) {
            int n = t >> 6, m = t & 63;
            const float* nr = nf + (size_t)n * NDIM;
            float s0 = nr[m];
            float3 s1 = ((const float3*)(nr + 64))[m];
            HU a, b;
            a.h = h2{(_Float16)s1.x, (_Float16)s1.y};
            b.h = h2{(_Float16)s1.z, (_Float16)s0};
            nft[t] = make_uint2(a.u, b.u);
        }
        return;
    }
    if (blockIdx.x >= (unsigned)LUT_BLOCKS) {
        int i = (blockIdx.x - LUT_BLOCKS) * 256 + threadIdx.x;
        if (i < E) rank[i] = atomicAdd(&counts[col[i]], 1);
        return;
    }

    __shared__ float h1s[4][64];
    __shared__ float h2s[4][64];
    int tid = threadIdx.x;
    int wave = tid >> 6;
    int j = tid & 63;
    int p = blockIdx.x * 4 + wave;
    float r = 0.5f + (4.5f / (float)(LUT_N - 1)) * (float)p;

    const float cnorm = 0.6324555320336759f;  // sqrt(2/5)
    float acc = b1[j];
    #pragma unroll
    for (int k = 0; k < 8; ++k) {
        float freq = (float)(k + 1) * (3.14159265358979323846f / 5.0f);
        acc = fmaf(cnorm * sinf(freq * r) / r, w1[k * 64 + j], acc);
    }
    h1s[wave][j] = acc / (1.0f + expf(-acc));
    __syncthreads();

    acc = b2[j];
    #pragma unroll 8
    for (int m = 0; m < 64; ++m) acc = fmaf(h1s[wave][m], w2[m * 64 + j], acc);
    h2s[wave][j] = acc / (1.0f + expf(-acc));
    __syncthreads();

    float u = r * 0.2f;
    float u5 = u * u * u * u * u;
    float env = (u < 1.0f) ? (1.0f - 21.0f * u5 + 35.0f * u5 * u - 15.0f * u5 * u * u) : 0.0f;

    float o0 = b3[j], o1 = b3[64 + j], o2 = b3[128 + j], o3 = b3[192 + j];
    #pragma unroll 8
    for (int m = 0; m < 64; ++m) {
        float hv = h2s[wave][m];
        const float* wr = w3 + m * 256;
        o0 = fmaf(hv, wr[j],       o0);
        o1 = fmaf(hv, wr[64 + j],  o1);
        o2 = fmaf(hv, wr[128 + j], o2);
        o3 = fmaf(hv, wr[192 + j], o3);
    }
    HU uab, ucd;
    uab.h = h2{(_Float16)(o0 * env), (_Float16)(o1 * env)};
    ucd.h = h2{(_Float16)(o2 * env), (_Float16)(o3 * env)};
    lutp[p * 64 + j] = make_uint2(uab.u, ucd.u);
}

// ---------------------------------------------------------------------------
// Coalesced per-chunk scan; chunk totals scanned in-wave by consumers.
// row_ptr[n] == loc[n] + boff[n >> 10], boff = wave-scan of btot.
// ---------------------------------------------------------------------------
__global__ __launch_bounds__(SCAN_BLK) void scan1_kernel(
    const int* __restrict__ counts, int* __restrict__ loc,
    int* __restrict__ btot, int N)
{
    __shared__ int sh[SCAN_BLK];
    int t = threadIdx.x;
    int idx = blockIdx.x * SCAN_BLK + t;
    int v = (idx < N) ? counts[idx] : 0;
    sh[t] = v;
    __syncthreads();
    int acc = v;
    for (int o = 1; o < SCAN_BLK; o <<= 1) {
        int add = (t >= o) ? sh[t - o] : 0;
        __syncthreads();
        acc += add;
        sh[t] = acc;
        __syncthreads();
    }
    if (idx <= N) loc[idx] = acc - v;   // exclusive within chunk
    if (t == SCAN_BLK - 1) btot[blockIdx.x] = acc;
}

// In-wave exclusive scan of btot (nb <= 64); lane i holds boff[i].
__device__ __forceinline__ int btot_scan(const int* __restrict__ btot, int nb, int lane)
{
    int v = (lane < nb) ? btot[lane] : 0;
    int acc = v;
    #pragma unroll
    for (int o = 1; o < 64; o <<= 1) {
        int up = __shfl_up(acc, o);
        if (lane >= o) acc += up;
    }
    return acc - v;
}

// ---------------------------------------------------------------------------
// Atomic-free scatter: p = loc[col] + boff[col>>10] + rank.
// em = uint4{ h2(shx,shy), h2(shz,0), rsrc | i0<<16, 0 }; N <= 65536.
// ---------------------------------------------------------------------------
__global__ __launch_bounds__(256) void scatter_kernel(
    const int* __restrict__ row, const int* __restrict__ col,
    const float* __restrict__ evec, const float* __restrict__ elen,
    int E, const int* __restrict__ loc, const int* __restrict__ btot, int nb,
    const int* __restrict__ rank, uint4* __restrict__ em)
{
    int lane = threadIdx.x & 63;
    int excl = btot_scan(btot, nb, lane);   // lane i: boff[i]

    int i = blockIdx.x * 256 + threadIdx.x;
    if (i < E) {
        int c = col[i];
        int p = loc[c] + __shfl(excl, c >> 10) + rank[i];
        float vx = evec[3 * i + 0], vy = evec[3 * i + 1], vz = evec[3 * i + 2];
        float inv = rsqrtf(vx * vx + vy * vy + vz * vz) * 1.7320508075688772f; // sqrt(3)/|v|
        float x = (elen[i] - 0.5f) * ((float)(LUT_N - 1) / 4.5f);
        int i0 = (int)(x + 0.5f);          // nearest-neighbor index
        i0 = i0 < 0 ? 0 : (i0 > LUT_N - 1 ? LUT_N - 1 : i0);
        HU a, b;
        a.h = h2{(_Float16)(vx * inv), (_Float16)(vy * inv)};
        b.h = h2{(_Float16)(vz * inv), (_Float16)0.0f};
        unsigned packed = (unsigned)row[i] | ((unsigned)i0 << 16);
        em[p] = make_uint4(a.u, b.u, packed, 0u);
    }
}

// ---------------------------------------------------------------------------
// Heavy kernel: 256-thread blocks = 4 INDEPENDENT waves, one node per wave
// (r16 proven config — r17's 16-stage pipeline regressed). Metadata em[j]
// wave-uniform -> SGPR s_load (start/end readfirstlane-forced). 8-stage
// named-variable pipeline with sched_barrier(0)-pinned {accum 4 | load 4}
// clusters. fp16 pair-packed epilogue. LUT shrunk to 2 MB (L2-resident).
// ---------------------------------------------------------------------------
struct St {
    uint2 L;                 // 4x fp16: wa,wb | wc,wd (nearest LUT entry)
    uint2 sv;                // half2(s1x,s1y), half2(s1z,s0)
    unsigned sh_xy, sh_z0;   // half2 bits (wave-uniform -> SGPR)
};

__device__ __forceinline__ St stage_load(int j, int lane,
                                         const uint4* __restrict__ em,
                                         const uint2* __restrict__ lutp,
                                         const uint2* __restrict__ nft)
{
    St s;
    uint4 md = em[j];                        // uniform address -> s_load_dwordx4
    s.sh_xy = md.x;
    s.sh_z0 = md.y;
    int rsrc = (int)(md.z & 0xFFFFu);
    int i0 = (int)(md.z >> 16);
    s.L = lutp[i0 * 64 + lane];
    s.sv = nft[(size_t)rsrc * 64 + lane];
    return s;
}

__device__ __forceinline__ void accum_st(const St& s, float& acc0, float& accx,
                                         float& accy, float& accz)
{
    HU lab, lcd, svxy, svzs, shxy, shz0;
    lab.u = s.L.x;  lcd.u = s.L.y;
    svxy.u = s.sv.x; svzs.u = s.sv.y; shxy.u = s.sh_xy; shz0.u = s.sh_z0;

    float wa = (float)lab.h.x, wb = (float)lab.h.y;
    float wc = (float)lcd.h.x, wd = (float)lcd.h.y;

    // dot = s1 . sh   (second fdot2's y-lane multiplies by packed 0)
    float dot = fdot2f(s.sv.x, s.sh_xy, 0.0f);
    dot = fdot2f(s.sv.y, s.sh_z0, dot);

    float s0 = (float)svzs.h.y;
    acc0 = fmaf(wa, s0, fmaf(wd, dot, acc0));
    float wcs0 = wc * s0;
    accx = fmaf(wb, (float)svxy.h.x, fmaf(wcs0, (float)shxy.h.x, accx));
    accy = fmaf(wb, (float)svxy.h.y, fmaf(wcs0, (float)shxy.h.y, accy));
    accz = fmaf(wb, (float)svzs.h.x, fmaf(wcs0, (float)shz0.h.x, accz));
}

__global__ __launch_bounds__(256, 4) void node_kernel(
    const float* __restrict__ nf,
    const uint2* __restrict__ nft,
    const uint2* __restrict__ lutp,
    const int* __restrict__ loc,
    const int* __restrict__ btot, int nb,
    const uint4* __restrict__ em,
    const uint2* __restrict__ lwpk,
    const float* __restrict__ g0,
    const float* __restrict__ be0,
    const float* __restrict__ g1,
    float* __restrict__ out,
    int N)
{
    __shared__ uint4 agp[4][32];   // [wave][pair] = fp16x2 {a0,x,y,z} pairs
    int tid = threadIdx.x;
    int wave = tid >> 6;
    int lane = tid & 63;
    int n = blockIdx.x * 4 + wave;

    int excl = btot_scan(btot, nb, lane);   // lane i: boff[i]

    if (n >= N) return;               // wave-uniform exit, no barriers used

    int start = loc[n]     + __shfl(excl, n >> 10);
    int end   = loc[n + 1] + __shfl(excl, (n + 1) >> 10);
    start = __builtin_amdgcn_readfirstlane(start);   // keep em[j] on scalar path
    end   = __builtin_amdgcn_readfirstlane(end);

    float acc0 = 0.0f, accx = 0.0f, accy = 0.0f, accz = 0.0f;

    int j = start;
    if (end - start >= 8) {
        St s0 = stage_load(j + 0, lane, em, lutp, nft);
        St s1 = stage_load(j + 1, lane, em, lutp, nft);
        St s2 = stage_load(j + 2, lane, em, lutp, nft);
        St s3 = stage_load(j + 3, lane, em, lutp, nft);
        St s4 = stage_load(j + 4, lane, em, lutp, nft);
        St s5 = stage_load(j + 5, lane, em, lutp, nft);
        St s6 = stage_load(j + 6, lane, em, lutp, nft);
        St s7 = stage_load(j + 7, lane, em, lutp, nft);
        j += 8;
        for (; j + 8 <= end; j += 8) {
            __builtin_amdgcn_sched_barrier(0);
            accum_st(s0, acc0, accx, accy, accz);
            accum_st(s1, acc0, accx, accy, accz);
            accum_st(s2, acc0, accx, accy, accz);
            accum_st(s3, acc0, accx, accy, accz);
            __builtin_amdgcn_sched_barrier(0);
            s0 = stage_load(j + 0, lane, em, lutp, nft);
            s1 = stage_load(j + 1, lane, em, lutp, nft);
            s2 = stage_load(j + 2, lane, em, lutp, nft);
            s3 = stage_load(j + 3, lane, em, lutp, nft);
            __builtin_amdgcn_sched_barrier(0);
            accum_st(s4, acc0, accx, accy, accz);
            accum_st(s5, acc0, accx, accy, accz);
            accum_st(s6, acc0, accx, accy, accz);
            accum_st(s7, acc0, accx, accy, accz);
            __builtin_amdgcn_sched_barrier(0);
            s4 = stage_load(j + 4, lane, em, lutp, nft);
            s5 = stage_load(j + 5, lane, em, lutp, nft);
            s6 = stage_load(j + 6, lane, em, lutp, nft);
            s7 = stage_load(j + 7, lane, em, lutp, nft);
        }
        __builtin_amdgcn_sched_barrier(0);
        accum_st(s0, acc0, accx, accy, accz);
        accum_st(s1, acc0, accx, accy, accz);
        accum_st(s2, acc0, accx, accy, accz);
        accum_st(s3, acc0, accx, accy, accz);
        accum_st(s4, acc0, accx, accy, accz);
        accum_st(s5, acc0, accx, accy, accz);
        accum_st(s6, acc0, accx, accy, accz);
        accum_st(s7, acc0, accx, accy, accz);
    }
    for (; j < end; ++j) {
        St s = stage_load(j, lane, em, lutp, nft);
        accum_st(s, acc0, accx, accy, accz);
    }

    // Pair-pack agg to fp16 and stash in LDS (even lanes write pair lane>>1).
    const float INVS2 = 0.7071067811865476f;
    float v0 = acc0 * INVS2, v1 = accx * INVS2, v2 = accy * INVS2, v3 = accz * INVS2;
    float p0 = __shfl_xor(v0, 1);
    float p1 = __shfl_xor(v1, 1);
    float p2 = __shfl_xor(v2, 1);
    float p3 = __shfl_xor(v3, 1);
    if (!(lane & 1)) {
        HU u0, u1, u2, u3;
        u0.g = __builtin_amdgcn_cvt_pkrtz(v0, p0);
        u1.g = __builtin_amdgcn_cvt_pkrtz(v1, p1);
        u2.g = __builtin_amdgcn_cvt_pkrtz(v2, p2);
        u3.g = __builtin_amdgcn_cvt_pkrtz(v3, p3);
        agp[wave][lane >> 1] = make_uint4(u0.u, u1.u, u2.u, u3.u);
    }
    // wave-private LDS; DS pipe in-order within a wave -> no barrier

    float a0 = 0.0f, t1x = 0.0f, t1y = 0.0f, t1z = 0.0f;
    #pragma unroll 8
    for (int i = 0; i < 32; ++i) {
        uint2 wp = lwpk[i * 64 + lane];   // h2(w0 pair), h2(w1 pair)
        uint4 gp = agp[wave][i];          // broadcast ds_read_b128
        a0  = fdot2f(gp.x, wp.x, a0);
        t1x = fdot2f(gp.y, wp.y, t1x);
        t1y = fdot2f(gp.z, wp.y, t1y);
        t1z = fdot2f(gp.w, wp.y, t1z);
    }
    const float sc = 0.125f;  // 1/sqrt(64)
    a0 *= sc; t1x *= sc; t1y *= sc; t1z *= sc;

    // layernorm over a0 across 64 lanes
    float mu = a0;
    #pragma unroll
    for (int o = 32; o > 0; o >>= 1) mu += __shfl_xor(mu, o);
    mu *= (1.0f / 64.0f);
    float d = a0 - mu;
    float var = d * d;
    #pragma unroll
    for (int o = 32; o > 0; o >>= 1) var += __shfl_xor(var, o);
    var *= (1.0f / 64.0f);
    float o0 = g0[lane] * d * rsqrtf(var + 1e-5f) + be0[lane];

    // RMS over vnorm2 across 64 lanes
    float vn = t1x * t1x + t1y * t1y + t1z * t1z;
    float ms = vn;
    #pragma unroll
    for (int o = 32; o > 0; o >>= 1) ms += __shfl_xor(ms, o);
    ms *= (1.0f / 64.0f);
    float rinv = rsqrtf(ms + 1e-5f);
    float gg = g1[lane];

    size_t b = (size_t)n * NDIM;
    out[b + lane] = nf[b + lane] + o0;
    float3 rv = ((const float3*)(nf + b + 64))[lane];
    float3 ov;
    ov.x = rv.x + gg * t1x * rinv;
    ov.y = rv.y + gg * t1y * rinv;
    ov.z = rv.z + gg * t1z * rinv;
    ((float3*)(out + b + 64))[lane] = ov;
}

// ---------------------------------------------------------------------------
extern "C" void kernel_launch(void* const* d_in, const int* in_sizes, int n_in,
                              void* d_out, int out_size, void* d_ws, size_t ws_size,
                              hipStream_t stream)
{
    const float* nf   = (const float*)d_in[0];
    const int*   eidx = (const int*)d_in[1];
    const float* evec = (const float*)d_in[2];
    const float* elen = (const float*)d_in[3];
    const float* w1   = (const float*)d_in[4];
    const float* b1   = (const float*)d_in[5];
    const float* w2   = (const float*)d_in[6];
    const float* b2   = (const float*)d_in[7];
    const float* w3   = (const float*)d_in[8];
    const float* b3   = (const float*)d_in[9];
    const float* lw0  = (const float*)d_in[10];
    const float* lw1  = (const float*)d_in[11];
    const float* g0   = (const float*)d_in[12];
    const float* be0  = (const float*)d_in[13];
    const float* g1   = (const float*)d_in[14];

    int N = in_sizes[0] / NDIM;
    int E = in_sizes[3];

    int nb = (N + SCAN_BLK) / SCAN_BLK;   // chunks covering idx range [0, N]

    char* ws = (char*)d_ws;
    size_t off_b = 0;
    auto align256 = [&]() { off_b = (off_b + 255) & ~(size_t)255; };
    uint2* lutp = (uint2*)(ws + off_b);   off_b += (size_t)LUT_N * 64 * 8;    align256();
    int* counts = (int*)(ws + off_b);     off_b += (size_t)N * 4;             align256();
    int* loc = (int*)(ws + off_b);        off_b += (size_t)(N + 1) * 4;       align256();
    int* btot = (int*)(ws + off_b);       off_b += (size_t)nb * 4;            align256();
    int* rank = (int*)(ws + off_b);       off_b += (size_t)E * 4;             align256();
    uint4* em = (uint4*)(ws + off_b);     off_b += (size_t)E * 16;            align256();
    uint2* nft = (uint2*)(ws + off_b);    off_b += (size_t)N * 64 * 8;        align256();
    uint2* lwpk = (uint2*)(ws + off_b);   off_b += (size_t)32 * 64 * 8;

    const int* row = eidx;
    const int* col = eidx + E;

    int histBlocks = (E + 255) / 256;
    int tBlocks = (N * 64 + 255) / 256;
    int lwBlocks = (32 * 64 + 255) / 256;

    hipMemsetAsync(counts, 0, (size_t)N * 4, stream);
    prep_kernel<<<LUT_BLOCKS + histBlocks + tBlocks + lwBlocks, 256, 0, stream>>>(
        w1, b1, w2, b2, w3, b3, lutp, col, E, counts, rank, nf, nft,
        lw0, lw1, lwpk, histBlocks, tBlocks, N);
    scan1_kernel<<<nb, SCAN_BLK, 0, stream>>>(counts, loc, btot, N);
    scatter_kernel<<<(E + 255) / 256, 256, 0, stream>>>(row, col, evec, elen, E,
                                                        loc, btot, nb, rank, em);
    node_kernel<<<(N + 3) / 4, 256, 0, stream>>>(nf, nft, lutp, loc, btot, nb, em,
                                                 lwpk, g0, be0, g1,
                                                 (float*)d_out, N);
}